// Round 6
// baseline (288.764 us; speedup 1.0000x reference)
//
#include <hip/hip_runtime.h>
#include <hip/hip_bf16.h>

typedef __attribute__((ext_vector_type(8))) short bf16x8;
typedef __attribute__((ext_vector_type(4))) float f32x4;
typedef __attribute__((ext_vector_type(16))) float f32x16;

#define D_MODEL 768
#define N_HEADS 12
#define D_HEAD  64
#define SEQ     4096
#define BATCH   2
#define MROWS   (BATCH * SEQ)          // 8192
#define QKV_N   (3 * D_MODEL)          // 2304
#define SCL     0.18033688011112042f   // (1/8) * log2(e)

// ---------------------------------------------------------------------------
// f32 -> bf16 conversion
// ---------------------------------------------------------------------------
__global__ __launch_bounds__(256) void f32_to_bf16(const float* __restrict__ in,
                                                   unsigned short* __restrict__ out,
                                                   int n4) {
    int i = blockIdx.x * blockDim.x + threadIdx.x;
    if (i >= n4) return;
    const float4 v = *(const float4*)(in + (size_t)i * 4);
    ushort4 o;
    o.x = __bfloat16_as_ushort(__float2bfloat16(v.x));
    o.y = __bfloat16_as_ushort(__float2bfloat16(v.y));
    o.z = __bfloat16_as_ushort(__float2bfloat16(v.z));
    o.w = __bfloat16_as_ushort(__float2bfloat16(v.w));
    *(ushort4*)(out + (size_t)i * 4) = o;
}

// ---------------------------------------------------------------------------
// GEMM: C[M,N] = A[M,K] * B[N,K]^T  (bf16, f32 acc), 128x128 tile, BK=64.
// ---------------------------------------------------------------------------
#define BM 128
#define BN 128
#define BK 64

template <bool OUT_F32>
__global__ __launch_bounds__(256) void gemm_bt(const short* __restrict__ A,
                                               const short* __restrict__ B,
                                               float* __restrict__ Cf,
                                               unsigned short* __restrict__ Cb,
                                               int M, int N, int K) {
    __shared__ __align__(16) short As[BM][BK];
    __shared__ __align__(16) short Bs[BN][BK];

    const int tid  = threadIdx.x;
    const int m0   = blockIdx.y * BM;
    const int n0   = blockIdx.x * BN;
    const int w    = tid >> 6;
    const int lane = tid & 63;
    const int wr   = w >> 1, wc = w & 1;
    const int lr   = lane & 15, lhi = lane >> 4;

    f32x4 acc[4][4];
#pragma unroll
    for (int i = 0; i < 4; i++)
#pragma unroll
        for (int j = 0; j < 4; j++)
#pragma unroll
            for (int e = 0; e < 4; e++) acc[i][j][e] = 0.0f;

    for (int k0 = 0; k0 < K; k0 += BK) {
        __syncthreads();
#pragma unroll
        for (int s = 0; s < 4; ++s) {
            int seg = tid + s * 256;
            int row = seg >> 3;
            int g   = seg & 7;
            int dst = (g ^ (row & 7)) * 8;
            *(bf16x8*)&As[row][dst] = *(const bf16x8*)&A[(size_t)(m0 + row) * K + k0 + g * 8];
            *(bf16x8*)&Bs[row][dst] = *(const bf16x8*)&B[(size_t)(n0 + row) * K + k0 + g * 8];
        }
        __syncthreads();
#pragma unroll
        for (int c = 0; c < 2; ++c) {
            bf16x8 af[4], bfr[4];
#pragma unroll
            for (int mi = 0; mi < 4; mi++) {
                int row = wr * 64 + mi * 16 + lr;
                af[mi] = *(const bf16x8*)&As[row][((c * 4 + lhi) ^ (lr & 7)) * 8];
            }
#pragma unroll
            for (int ni = 0; ni < 4; ni++) {
                int row = wc * 64 + ni * 16 + lr;
                bfr[ni] = *(const bf16x8*)&Bs[row][((c * 4 + lhi) ^ (lr & 7)) * 8];
            }
#pragma unroll
            for (int mi = 0; mi < 4; mi++)
#pragma unroll
                for (int ni = 0; ni < 4; ni++)
                    acc[mi][ni] = __builtin_amdgcn_mfma_f32_16x16x32_bf16(af[mi], bfr[ni], acc[mi][ni], 0, 0, 0);
        }
    }

#pragma unroll
    for (int mi = 0; mi < 4; mi++)
#pragma unroll
        for (int ni = 0; ni < 4; ni++)
#pragma unroll
            for (int r = 0; r < 4; r++) {
                int row = m0 + wr * 64 + mi * 16 + lhi * 4 + r;
                int col = n0 + wc * 64 + ni * 16 + lr;
                float v = acc[mi][ni][r];
                if (OUT_F32)
                    Cf[(size_t)row * N + col] = v;
                else
                    Cb[(size_t)row * N + col] = __bfloat16_as_ushort(__float2bfloat16(v));
            }
}

// ---------------------------------------------------------------------------
// V transpose: qkv V-region (b,t,h,d) -> vt[bh*64+d][t]  (bf16)
// ---------------------------------------------------------------------------
__global__ __launch_bounds__(256) void v_transpose(const short* __restrict__ qkv,
                                                   short* __restrict__ vt) {
    __shared__ short S[64][72];
    const int tid = threadIdx.x;
    const int t0  = blockIdx.x * 64;
    const int bh  = blockIdx.y;
    const int b   = bh / N_HEADS, h = bh % N_HEADS;
#pragma unroll
    for (int s = 0; s < 2; s++) {
        int tl = (tid >> 3) + 32 * s, dg = tid & 7;
        *(bf16x8*)&S[tl][dg * 8] =
            *(const bf16x8*)&qkv[((size_t)(b * SEQ + t0 + tl)) * QKV_N + 2 * D_MODEL + h * D_HEAD + dg * 8];
    }
    __syncthreads();
#pragma unroll
    for (int ii = 0; ii < 2; ii++) {
        int d = (tid >> 3) + 32 * ii, tg = tid & 7;
        bf16x8 v;
#pragma unroll
        for (int j = 0; j < 8; j++) v[j] = S[tg * 8 + j][d];
        *(bf16x8*)&vt[((size_t)bh * 64 + d) * SEQ + t0 + tg * 8] = v;
    }
}

// ---------------------------------------------------------------------------
// Flash attention, 32x32 MFMA structure (m214-style).
// Block = 4 waves x 32 q-rows = 128 q-rows. Grid x: 32 q-blocks heavy-first.
// S^T = mfma32(K, Q): lane holds S[k=(reg&3)+8*(reg>>2)+4*hi][q=lane&31].
// P -> PV A-frags via cvt_pk_bf16 + v_permlane32_swap (in-register, no LDS).
// ---------------------------------------------------------------------------
__device__ __forceinline__ unsigned cvt_pk_bf16(float lo, float hi) {
    unsigned r;
    asm("v_cvt_pk_bf16_f32 %0, %1, %2" : "=v"(r) : "v"(lo), "v"(hi));
    return r;
}

__global__ __launch_bounds__(256) void attn_fwd(const short* __restrict__ qkv,
                                                const short* __restrict__ vt,
                                                unsigned short* __restrict__ out) {
    __shared__ __align__(16) short Ks[64][64];   // K tile  [kv][d]  (swizzled granules)
    __shared__ __align__(16) short Vs[64][64];   // V^T tile [d][kv] (swizzled granules)

    const int tid  = threadIdx.x;
    const int w    = tid >> 6;
    const int lane = tid & 63;
    const int l31  = lane & 31;          // q (softmax-land) / k-row / d-row
    const int hi   = lane >> 5;
    const int swz  = l31 & 7;
    const int i    = 31 - (int)blockIdx.x;       // heavy-first
    const int bh   = blockIdx.y;
    const int b    = bh / N_HEADS, h = bh % N_HEADS;
    const size_t rowbase = (size_t)b * SEQ;
    const int q0   = i * 128;
    const int qw   = q0 + w * 32;                // wave's first q-row
    const int qg   = qw + l31;                   // this lane's q (softmax-land)
    const int srow = tid >> 3, sg = tid & 7;

    // Q fragments (B operand): qf[c][j] = Q[qg][c*16 + hi*8 + j]
    bf16x8 qf[4];
    {
        const short* qp = &qkv[(rowbase + qg) * QKV_N + h * D_HEAD + hi * 8];
#pragma unroll
        for (int c = 0; c < 4; c++) qf[c] = *(const bf16x8*)&qp[c * 16];
    }

    float m_ = -INFINITY, l_ = 0.0f;
    f32x16 oacc[2];
#pragma unroll
    for (int nd = 0; nd < 2; nd++)
#pragma unroll
        for (int e = 0; e < 16; e++) oacc[nd][e] = 0.0f;

    const int nj = 2 * i + 2;   // kv tiles for this block

    // prefetch tile 0
    bf16x8 kp[2], vp[2];
#pragma unroll
    for (int s = 0; s < 2; s++) {
        int row = srow + 32 * s;
        kp[s] = *(const bf16x8*)&qkv[(rowbase + row) * QKV_N + D_MODEL + h * D_HEAD + sg * 8];
        vp[s] = *(const bf16x8*)&vt[((size_t)bh * 64 + row) * SEQ + sg * 8];
    }

    for (int jt = 0; jt < nj; jt++) {
        const int j0 = jt * 64;
        __syncthreads();
#pragma unroll
        for (int s = 0; s < 2; s++) {
            int row = srow + 32 * s;
            int dst = (sg ^ (row & 7)) * 8;
            *(bf16x8*)&Ks[row][dst] = kp[s];
            *(bf16x8*)&Vs[row][dst] = vp[s];
        }
        {
            int jn = (jt + 1 < nj) ? j0 + 64 : 0;
#pragma unroll
            for (int s = 0; s < 2; s++) {
                int row = srow + 32 * s;
                kp[s] = *(const bf16x8*)&qkv[(rowbase + jn + row) * QKV_N + D_MODEL + h * D_HEAD + sg * 8];
                vp[s] = *(const bf16x8*)&vt[((size_t)bh * 64 + row) * SEQ + jn + sg * 8];
            }
        }
        __syncthreads();

        if (j0 > qw + 31) continue;   // fully masked for this wave (barriers already done)

        // ---- S^T = K · Q^T : two 32x32 subtiles (kv 0..31, 32..63) ----
        f32x16 sa0, sa1;
#pragma unroll
        for (int e = 0; e < 16; e++) { sa0[e] = 0.0f; sa1[e] = 0.0f; }
#pragma unroll
        for (int c = 0; c < 4; c++) {
            bf16x8 kf0 = *(const bf16x8*)&Ks[l31][((2 * c + hi) ^ swz) * 8];
            bf16x8 kf1 = *(const bf16x8*)&Ks[32 + l31][((2 * c + hi) ^ swz) * 8];
            sa0 = __builtin_amdgcn_mfma_f32_32x32x16_bf16(kf0, qf[c], sa0, 0, 0, 0);
            sa1 = __builtin_amdgcn_mfma_f32_32x32x16_bf16(kf1, qf[c], sa1, 0, 0, 0);
        }

        // ---- causal mask ----
        if (j0 + 63 > qw) {
#pragma unroll
            for (int g = 0; g < 4; g++)
#pragma unroll
                for (int r = 0; r < 4; r++) {
                    int kloc = r + 8 * g + 4 * hi;
                    if (j0 + kloc > qg)      sa0[g * 4 + r] = -INFINITY;
                    if (j0 + 32 + kloc > qg) sa1[g * 4 + r] = -INFINITY;
                }
        }

        // ---- row max (in-lane 32 + cross-half) ----
        float mx = fmaxf(sa0[0], sa1[0]);
#pragma unroll
        for (int e = 1; e < 16; e++) mx = fmaxf(mx, fmaxf(sa0[e], sa1[e]));
        mx = fmaxf(mx, __shfl_xor(mx, 32, 64));
        float smax = mx * SCL;

        // T13 defer-max
        if (!__all(smax <= m_ + 8.0f)) {
            float mnew = fmaxf(m_, smax);
            float corr = __builtin_amdgcn_exp2f(m_ - mnew);
            m_ = mnew;
            l_ *= corr;
#pragma unroll
            for (int g = 0; g < 4; g++)
#pragma unroll
                for (int r = 0; r < 4; r++) {
                    float cf = __shfl(corr, r + 8 * g + 4 * hi, 64);
                    oacc[0][g * 4 + r] *= cf;
                    oacc[1][g * 4 + r] *= cf;
                }
        }

        // ---- P = exp2(S*SCL - m), row-sum ----
        float ls = 0.0f;
#pragma unroll
        for (int e = 0; e < 16; e++) {
            float p0 = __builtin_amdgcn_exp2f(fmaf(sa0[e], SCL, -m_));
            float p1 = __builtin_amdgcn_exp2f(fmaf(sa1[e], SCL, -m_));
            sa0[e] = p0; sa1[e] = p1;
            ls += p0 + p1;
        }
        ls += __shfl_xor(ls, 32, 64);
        l_ += ls;

        // ---- pack P to bf16, redistribute via permlane32_swap -> A-frags ----
        // lane holds k = 8g+4hi+{0..3} (per subtile); A-chunk needs k = hi*8+j.
        bf16x8 pa[4];   // [subtile*2 + chunk]
#pragma unroll
        for (int ks = 0; ks < 2; ks++) {
            unsigned X[4], U[4];
#pragma unroll
            for (int g = 0; g < 4; g++) {
                X[g] = cvt_pk_bf16(ks ? sa1[4 * g + 0] : sa0[4 * g + 0],
                                   ks ? sa1[4 * g + 1] : sa0[4 * g + 1]);
                U[g] = cvt_pk_bf16(ks ? sa1[4 * g + 2] : sa0[4 * g + 2],
                                   ks ? sa1[4 * g + 3] : sa0[4 * g + 3]);
            }
            asm("v_permlane32_swap_b32 %0, %1" : "+v"(X[0]), "+v"(X[1]));
            asm("v_permlane32_swap_b32 %0, %1" : "+v"(U[0]), "+v"(U[1]));
            asm("v_permlane32_swap_b32 %0, %1" : "+v"(X[2]), "+v"(X[3]));
            asm("v_permlane32_swap_b32 %0, %1" : "+v"(U[2]), "+v"(U[3]));
            union { unsigned u[4]; bf16x8 v; } p0, p1;
            p0.u[0] = X[0]; p0.u[1] = U[0]; p0.u[2] = X[1]; p0.u[3] = U[1];
            p1.u[0] = X[2]; p1.u[1] = U[2]; p1.u[2] = X[3]; p1.u[3] = U[3];
            pa[ks * 2 + 0] = p0.v;
            pa[ks * 2 + 1] = p1.v;
        }

        // ---- O += P · V ----
#pragma unroll
        for (int nd = 0; nd < 2; nd++) {
#pragma unroll
            for (int kc = 0; kc < 4; kc++) {   // kc = ks*2+ck, k-16-chunk
                bf16x8 vb = *(const bf16x8*)&Vs[nd * 32 + l31][((kc * 2 + hi) ^ swz) * 8];
                oacc[nd] = __builtin_amdgcn_mfma_f32_32x32x16_bf16(pa[kc], vb, oacc[nd], 0, 0, 0);
            }
        }
    }

    // ---- epilogue: broadcast 1/l to oacc-land rows, store ----
    float li = 1.0f / l_;
    float lT[16];
#pragma unroll
    for (int g = 0; g < 4; g++)
#pragma unroll
        for (int r = 0; r < 4; r++) lT[g * 4 + r] = __shfl(li, r + 8 * g + 4 * hi, 64);
#pragma unroll
    for (int nd = 0; nd < 2; nd++)
#pragma unroll
        for (int g = 0; g < 4; g++)
#pragma unroll
            for (int r = 0; r < 4; r++) {
                int qrow = qw + r + 8 * g + 4 * hi;
                out[(rowbase + qrow) * D_MODEL + h * D_HEAD + nd * 32 + l31] =
                    __bfloat16_as_ushort(__float2bfloat16(oacc[nd][g * 4 + r] * lT[g * 4 + r]));
            }
}

// ---------------------------------------------------------------------------
extern "C" void kernel_launch(void* const* d_in, const int* in_sizes, int n_in,
                              void* d_out, int out_size, void* d_ws, size_t ws_size,
                              hipStream_t stream) {
    const float* x     = (const float*)d_in[0];
    const float* w_qkv = (const float*)d_in[1];
    const float* w_out = (const float*)d_in[2];
    float* outp        = (float*)d_out;

    char* ws = (char*)d_ws;
    size_t off = 0;
    auto alloc = [&](size_t bytes) -> void* {
        void* p = ws + off;
        off = (off + bytes + 255) & ~(size_t)255;
        return p;
    };
    unsigned short* xb    = (unsigned short*)alloc((size_t)MROWS * D_MODEL * 2);  // also attn out
    unsigned short* wqkvb = (unsigned short*)alloc((size_t)QKV_N * D_MODEL * 2);
    unsigned short* woutb = (unsigned short*)alloc((size_t)D_MODEL * D_MODEL * 2);
    unsigned short* qkvb  = (unsigned short*)alloc((size_t)MROWS * QKV_N * 2);
    unsigned short* vtb   = (unsigned short*)alloc((size_t)BATCH * N_HEADS * D_HEAD * SEQ * 2);

    {
        int n4 = MROWS * D_MODEL / 4;
        f32_to_bf16<<<(n4 + 255) / 256, 256, 0, stream>>>(x, xb, n4);
        n4 = QKV_N * D_MODEL / 4;
        f32_to_bf16<<<(n4 + 255) / 256, 256, 0, stream>>>(w_qkv, wqkvb, n4);
        n4 = D_MODEL * D_MODEL / 4;
        f32_to_bf16<<<(n4 + 255) / 256, 256, 0, stream>>>(w_out, woutb, n4);
    }

    // qkv = x @ w_qkv^T   (M=8192, N=2304, K=768) -> bf16
    gemm_bt<false><<<dim3(QKV_N / BN, MROWS / BM), 256, 0, stream>>>(
        (const short*)xb, (const short*)wqkvb, nullptr, qkvb, MROWS, QKV_N, D_MODEL);

    // V transpose: (b,t,h,d) -> [bh*64+d][t]
    v_transpose<<<dim3(SEQ / 64, BATCH * N_HEADS), 256, 0, stream>>>((const short*)qkvb, (short*)vtb);

    // attention: 32 q-blocks of 128 rows (heavy-first) x 24 bh
    attn_fwd<<<dim3(32, BATCH * N_HEADS), 256, 0, stream>>>(
        (const short*)qkvb, (const short*)vtb, xb);

    // out = attn @ w_out^T  (M=8192, N=768, K=768) -> f32
    gemm_bt<true><<<dim3(D_MODEL / BN, MROWS / BM), 256, 0, stream>>>(
        (const short*)xb, (const short*)woutb, outp, nullptr, MROWS, D_MODEL, D_MODEL);
}